// Round 1
// baseline (399.348 us; speedup 1.0000x reference)
//
#include <hip/hip_runtime.h>
#include <math.h>

// Problem constants (from reference setup_inputs)
#define BS    64
#define NROWS 4096          // H*W
#define CCH   128           // channels
#define NC4   32            // channels / 4
#define BPB   32            // blocks per batch for the big kernels

// ---------- helpers ----------

__device__ __forceinline__ float dot4(float4 a, float4 b) {
    return a.x*b.x + a.y*b.y + a.z*b.z + a.w*b.w;
}

// Sum across a 32-lane group (lanes [0..31] or [32..63] of a wave64).
// xor masks 1..16 never cross the 32-lane half boundary.
__device__ __forceinline__ float grp_reduce(float v) {
    v += __shfl_xor(v, 1);
    v += __shfl_xor(v, 2);
    v += __shfl_xor(v, 4);
    v += __shfl_xor(v, 8);
    v += __shfl_xor(v, 16);
    return v;
}

// Compute the tangent vector x_T at the origin (after logmap at mean and
// parallel transport mean->origin), for one row. Each 32-lane group holds one
// row; lane owns 4 channels (float4). c4 = lane&31, src = lane&32 (group base).
__device__ __forceinline__ float4 compute_xT(float4 xv, float4 mv, float mean0,
                                             float inv1pm0, int c4, int src) {
    // alpha = -linner(mean, x) = 2*mean0*x0 - dot(mean, x)
    float d = dot4(mv, xv);
    d = grp_reduce(d);
    float x0 = __shfl(xv.x, src);               // channel 0 of this row
    float alpha = fmaxf(fmaf(2.0f * mean0, x0, -d), 1.0f + 1e-7f);

    // u = x - alpha*mean
    float4 uv;
    uv.x = fmaf(-alpha, mv.x, xv.x);
    uv.y = fmaf(-alpha, mv.y, xv.y);
    uv.z = fmaf(-alpha, mv.z, xv.z);
    uv.w = fmaf(-alpha, mv.w, xv.w);
    float u0 = fmaf(-alpha, mean0, x0);

    // ||u||_L = sqrt(dot(u,u) - 2*u0^2)
    float uu = dot4(uv, uv);
    uu = grp_reduce(uu);
    float l_uu = fmaf(-2.0f * u0, u0, uu);
    float un = sqrtf(fmaxf(l_uu, 1e-8f));

    float fac = acoshf(alpha) / un;
    float4 tv;
    tv.x = fac * uv.x;
    tv.y = fac * uv.y;
    tv.z = fac * uv.z;
    tv.w = fac * uv.w;
    float xT0 = fac * u0;

    // parallel transport mean -> origin: tv -= (xT0/(1+mean0)) * (mean + e0)
    float tc = xT0 * inv1pm0;
    tv.x = fmaf(-tc, mv.x, tv.x);
    tv.y = fmaf(-tc, mv.y, tv.y);
    tv.z = fmaf(-tc, mv.z, tv.z);
    tv.w = fmaf(-tc, mv.w, tv.w);
    if (c4 == 0) tv.x -= tc;                    // e0 hits channel 0 only
    return tv;
}

// ---------- kernel 1: per-batch channel sums ----------
__global__ __launch_bounds__(256) void k_mean_sum(const float4* __restrict__ x,
                                                  float* __restrict__ msum) {
    int b   = blockIdx.x / BPB;
    int blk = blockIdx.x % BPB;
    int t   = threadIdx.x;
    int c4  = t & 31;
    int grp = t >> 5;                            // 0..7: 8 rows per iteration
    const int rows = NROWS / BPB;                // 128
    int row0 = blk * rows;
    const float4* xb = x + (size_t)b * NROWS * NC4;

    float4 acc = make_float4(0.f, 0.f, 0.f, 0.f);
    for (int r = row0 + grp; r < row0 + rows; r += 8) {
        float4 v = xb[(size_t)r * NC4 + c4];
        acc.x += v.x; acc.y += v.y; acc.z += v.z; acc.w += v.w;
    }
    __shared__ float4 lds[256];
    lds[t] = acc;
    __syncthreads();
    if (t < 32) {
        float4 s = lds[t];
        #pragma unroll
        for (int k = 1; k < 8; ++k) {
            float4 v = lds[t + 32 * k];
            s.x += v.x; s.y += v.y; s.z += v.z; s.w += v.w;
        }
        atomicAdd(&msum[b * CCH + 4 * t + 0], s.x);
        atomicAdd(&msum[b * CCH + 4 * t + 1], s.y);
        atomicAdd(&msum[b * CCH + 4 * t + 2], s.z);
        atomicAdd(&msum[b * CCH + 4 * t + 3], s.w);
    }
}

// ---------- kernel 2: normalize mean onto hyperboloid ----------
__global__ __launch_bounds__(128) void k_mean_norm(const float* __restrict__ msum,
                                                   float* __restrict__ mean) {
    int b = blockIdx.x;
    int c = threadIdx.x;                          // 0..127, 2 waves
    float m = msum[b * CCH + c] * (1.0f / (float)NROWS);
    float mm = m * m;
    // full wave64 reduce
    for (int k = 1; k <= 32; k <<= 1) mm += __shfl_xor(mm, k);
    __shared__ float red[2];
    __shared__ float m0sh;
    if ((c & 63) == 0) red[c >> 6] = mm;
    if (c == 0) m0sh = m;
    __syncthreads();
    float tot = red[0] + red[1];
    float m0  = m0sh;
    float val = fmaf(2.0f * m0, m0, -tot);        // -linner(m,m)
    float inv = 1.0f / sqrtf(fmaxf(val, 1e-8f));
    mean[b * CCH + c] = m * inv;
}

// ---------- kernel 3: Frechet variance accumulation ----------
__global__ __launch_bounds__(256) void k_var(const float4* __restrict__ x,
                                             const float* __restrict__ mean,
                                             float* __restrict__ varsum) {
    int b   = blockIdx.x / BPB;
    int blk = blockIdx.x % BPB;
    int t   = threadIdx.x;
    int c4  = t & 31;
    int grp = t >> 5;                             // 0..7
    int src = t & 32;                             // group base lane within wave

    const float* meanb = mean + b * CCH;
    float4 mv    = ((const float4*)meanb)[c4];
    float  mean0 = meanb[0];
    float  inv1pm0 = 1.0f / (1.0f + mean0);

    const float4* xb = x + (size_t)b * NROWS * NC4;
    const int rows = NROWS / BPB;
    int row0 = blk * rows;

    float nsum = 0.0f;
    for (int r = row0 + grp; r < row0 + rows; r += 8) {
        float4 xv = xb[(size_t)r * NC4 + c4];
        float4 tv = compute_xT(xv, mv, mean0, inv1pm0, c4, src);
        float n2 = dot4(tv, tv);
        n2 = grp_reduce(n2);                      // Euclidean norm^2 over 128 ch
        nsum += sqrtf(n2);
    }
    if (c4 == 0) atomicAdd(&varsum[b], nsum);
}

// ---------- kernel 4: final output ----------
__global__ __launch_bounds__(256) void k_out(const float4* __restrict__ x,
                                             const float* __restrict__ mean,
                                             const float* __restrict__ varsum,
                                             const float* __restrict__ beta,
                                             const float* __restrict__ gamma,
                                             float4* __restrict__ out) {
    int b   = blockIdx.x / BPB;
    int blk = blockIdx.x % BPB;
    int t   = threadIdx.x;
    int c4  = t & 31;
    int grp = t >> 5;
    int src = t & 32;

    const float* meanb = mean + b * CCH;
    float4 mv    = ((const float4*)meanb)[c4];
    float  mean0 = meanb[0];
    float  inv1pm0 = 1.0f / (1.0f + mean0);

    float4 bv    = ((const float4*)beta)[c4];
    float  beta0 = beta[0];
    float  invb  = 1.0f / (1.0f + beta0);
    float  scale = gamma[0] / (varsum[b] * (1.0f / (float)NROWS) + 1e-5f);

    const float4* xb = x + (size_t)b * NROWS * NC4;
    float4*       ob = out + (size_t)b * NROWS * NC4;
    const int rows = NROWS / BPB;
    int row0 = blk * rows;

    for (int r = row0 + grp; r < row0 + rows; r += 8) {
        float4 xv = xb[(size_t)r * NC4 + c4];
        float4 tv = compute_xT(xv, mv, mean0, inv1pm0, c4, src);

        // gamma / (var + eps)
        tv.x *= scale; tv.y *= scale; tv.z *= scale; tv.w *= scale;

        // PT origin -> beta: tv += (linner(beta,tv)/(1+beta0)) * (beta + e0)
        float db = dot4(bv, tv);
        db = grp_reduce(db);
        float xT0 = __shfl(tv.x, src);
        float lb  = fmaf(-2.0f * beta0, xT0, db);
        float pt  = lb * invb;
        tv.x = fmaf(pt, bv.x, tv.x);
        tv.y = fmaf(pt, bv.y, tv.y);
        tv.z = fmaf(pt, bv.z, tv.z);
        tv.w = fmaf(pt, bv.w, tv.w);
        if (c4 == 0) tv.x += pt;

        // expmap at beta: nu = sqrt(clip(linner(tv,tv),1e-8))
        float dt = dot4(tv, tv);
        dt = grp_reduce(dt);
        float xT0b = __shfl(tv.x, src);
        float nu2  = fmaf(-2.0f * xT0b, xT0b, dt);
        float nu   = sqrtf(fmaxf(nu2, 1e-8f));
        float chn  = coshf(nu);
        float shn  = sinhf(nu) / nu;

        float4 ov;
        ov.x = fmaf(chn, bv.x, shn * tv.x);
        ov.y = fmaf(chn, bv.y, shn * tv.y);
        ov.z = fmaf(chn, bv.z, shn * tv.z);
        ov.w = fmaf(chn, bv.w, shn * tv.w);
        ob[(size_t)r * NC4 + c4] = ov;
    }
}

// ---------- launch ----------
extern "C" void kernel_launch(void* const* d_in, const int* in_sizes, int n_in,
                              void* d_out, int out_size, void* d_ws, size_t ws_size,
                              hipStream_t stream) {
    const float* x     = (const float*)d_in[0];
    const float* beta  = (const float*)d_in[1];
    const float* gamma = (const float*)d_in[2];
    float*       out   = (float*)d_out;

    float* ws     = (float*)d_ws;
    float* msum   = ws;                 // BS*CCH  = 8192 floats
    float* varsum = ws + BS * CCH;      // BS      = 64 floats
    float* mean   = ws + BS * CCH + BS; // BS*CCH  = 8192 floats

    // zero the atomic accumulators (ws is poisoned 0xAA before every launch)
    hipMemsetAsync(ws, 0, (BS * CCH + BS) * sizeof(float), stream);

    k_mean_sum<<<dim3(BS * BPB), dim3(256), 0, stream>>>((const float4*)x, msum);
    k_mean_norm<<<dim3(BS), dim3(128), 0, stream>>>(msum, mean);
    k_var<<<dim3(BS * BPB), dim3(256), 0, stream>>>((const float4*)x, mean, varsum);
    k_out<<<dim3(BS * BPB), dim3(256), 0, stream>>>((const float4*)x, mean, varsum,
                                                    beta, gamma, (float4*)out);
}

// Round 2
// 350.321 us; speedup vs baseline: 1.1399x; 1.1399x over previous
//
#include <hip/hip_runtime.h>
#include <math.h>

// Problem constants (from reference setup_inputs)
#define BS    64
#define NROWS 4096          // H*W
#define CCH   128           // channels
#define NC4   32            // channels / 4
#define BPB   32            // blocks per batch
#define RPB   (NROWS/BPB)   // 128 rows per block

typedef float vf4 __attribute__((ext_vector_type(4)));

__device__ __forceinline__ float dot4(float4 a, float4 b) {
    return a.x*b.x + a.y*b.y + a.z*b.z + a.w*b.w;
}

// Sum across a 32-lane group (xor masks 1..16 stay within wave64 halves).
__device__ __forceinline__ float grp_reduce(float v) {
    v += __shfl_xor(v, 1);
    v += __shfl_xor(v, 2);
    v += __shfl_xor(v, 4);
    v += __shfl_xor(v, 8);
    v += __shfl_xor(v, 16);
    return v;
}

// ---------- kernel 1: per-batch channel sums ----------
__global__ __launch_bounds__(256) void k_mean_sum(const float4* __restrict__ x,
                                                  float* __restrict__ msum) {
    int b   = blockIdx.x / BPB;
    int blk = blockIdx.x % BPB;
    int t   = threadIdx.x;
    int c4  = t & 31;
    int grp = t >> 5;
    int row0 = blk * RPB;
    const float4* xb = x + (size_t)b * NROWS * NC4;

    float4 acc = make_float4(0.f, 0.f, 0.f, 0.f);
    for (int r = row0 + grp; r < row0 + RPB; r += 8) {
        float4 v = xb[(size_t)r * NC4 + c4];
        acc.x += v.x; acc.y += v.y; acc.z += v.z; acc.w += v.w;
    }
    __shared__ float4 lds[256];
    lds[t] = acc;
    __syncthreads();
    if (t < 32) {
        float4 s = lds[t];
        #pragma unroll
        for (int k = 1; k < 8; ++k) {
            float4 v = lds[t + 32 * k];
            s.x += v.x; s.y += v.y; s.z += v.z; s.w += v.w;
        }
        atomicAdd(&msum[b * CCH + 4 * t + 0], s.x);
        atomicAdd(&msum[b * CCH + 4 * t + 1], s.y);
        atomicAdd(&msum[b * CCH + 4 * t + 2], s.z);
        atomicAdd(&msum[b * CCH + 4 * t + 3], s.w);
    }
}

// ---------- kernel 2: normalize mean + linner(beta, mean) ----------
__global__ __launch_bounds__(128) void k_mean_norm(const float* __restrict__ msum,
                                                   const float* __restrict__ beta,
                                                   float* __restrict__ mean,
                                                   float* __restrict__ lbm) {
    int b = blockIdx.x;
    int c = threadIdx.x;                          // 0..127, 2 waves
    float m  = msum[b * CCH + c] * (1.0f / (float)NROWS);
    float bc = beta[c];
    float mm = m * m;
    float bm = bc * m;
    for (int k = 1; k <= 32; k <<= 1) { mm += __shfl_xor(mm, k); bm += __shfl_xor(bm, k); }
    __shared__ float rmm[2], rbm[2], m0sh;
    if ((c & 63) == 0) { rmm[c >> 6] = mm; rbm[c >> 6] = bm; }
    if (c == 0) m0sh = m;
    __syncthreads();
    float smm = rmm[0] + rmm[1];
    float sbm = rbm[0] + rbm[1];
    float m0  = m0sh;
    float val = fmaf(2.0f * m0, m0, -smm);        // -linner(m,m)
    float inv = 1.0f / sqrtf(fmaxf(val, 1e-8f));
    mean[b * CCH + c] = m * inv;
    if (c == 0) {
        float b0 = beta[0];
        lbm[b] = (sbm - 2.0f * b0 * m0) * inv;    // linner(beta, mean)
    }
}

// ---------- kernel 3 (fast): variance + per-row params ----------
__global__ __launch_bounds__(256) void k_var_fast(const float4* __restrict__ x,
                                                  const float* __restrict__ mean,
                                                  const float* __restrict__ beta,
                                                  const float* __restrict__ lbm,
                                                  float* __restrict__ varsum,
                                                  float4* __restrict__ rowp) {
    int b   = blockIdx.x / BPB;
    int blk = blockIdx.x % BPB;
    int t   = threadIdx.x;
    int c4  = t & 31;
    int grp = t >> 5;
    int src = t & 32;

    const float* meanb = mean + b * CCH;
    float4 mv = ((const float4*)meanb)[c4];
    float  m0 = meanb[0];
    float  inv1pm0 = 1.0f / (1.0f + m0);
    float4 bv = ((const float4*)beta)[c4];
    float  b0 = beta[0];
    float  lbmb = lbm[b];

    const float4* xb = x + (size_t)b * NROWS * NC4;
    int row0 = blk * RPB;

    float nsum = 0.0f;
    for (int r = row0 + grp; r < row0 + RPB; r += 8) {
        float4 xv = xb[(size_t)r * NC4 + c4];
        float d = dot4(mv, xv);
        float e = dot4(bv, xv);
        // interleaved dual reduce for ILP
        d += __shfl_xor(d, 1);  e += __shfl_xor(e, 1);
        d += __shfl_xor(d, 2);  e += __shfl_xor(e, 2);
        d += __shfl_xor(d, 4);  e += __shfl_xor(e, 4);
        d += __shfl_xor(d, 8);  e += __shfl_xor(e, 8);
        d += __shfl_xor(d, 16); e += __shfl_xor(e, 16);
        float x0 = __shfl(xv.x, src);
        float alpha = fmaxf(fmaf(2.0f * m0, x0, -d), 1.0f + 1e-7f);
        float h = acoshf(alpha);                  // = ||x_T||  (PT isometry, xT0 == 0)
        nsum += h;
        float un  = sqrtf(fmaxf(fmaf(alpha, alpha, -1.0f), 1e-8f)); // ||u||_L = sqrt(a^2-1)
        float fac = h / un;
        float u0  = fmaf(-alpha, m0, x0);
        float tc  = fac * u0 * inv1pm0;
        float s_m = fmaf(fac, alpha, tc);         // x_T = fac*x - s_m*mean - tc*e0
        float lbx = fmaf(-2.0f * b0, x0, e);      // linner(beta, x)
        float pb  = fmaf(fac, lbx, fmaf(-s_m, lbmb, tc * b0)); // linner(beta, x_T)
        if (c4 == 0) rowp[(size_t)b * NROWS + r] = make_float4(fac, alpha, tc, pb);
    }
    if (c4 == 0) atomicAdd(&varsum[b], nsum);
}

// ---------- kernel 4 (fast): reduction-free output ----------
__global__ __launch_bounds__(256) void k_out_fast(const float4* __restrict__ x,
                                                  const float* __restrict__ mean,
                                                  const float* __restrict__ varsum,
                                                  const float* __restrict__ beta,
                                                  const float* __restrict__ gamma,
                                                  const float4* __restrict__ rowp,
                                                  float4* __restrict__ out) {
    int b   = blockIdx.x / BPB;
    int blk = blockIdx.x % BPB;
    int t   = threadIdx.x;
    int c4  = t & 31;
    int grp = t >> 5;

    const float* meanb = mean + b * CCH;
    float4 mv = ((const float4*)meanb)[c4];
    float4 bv = ((const float4*)beta)[c4];
    float  b0 = beta[0];
    float  invb  = 1.0f / (1.0f + b0);
    float  scale = gamma[0] / (varsum[b] * (1.0f / (float)NROWS) + 1e-5f);

    const float4* xb = x + (size_t)b * NROWS * NC4;
    float4*       ob = out + (size_t)b * NROWS * NC4;
    int row0 = blk * RPB;

    for (int r = row0 + grp; r < row0 + RPB; r += 8) {
        float4 xv = xb[(size_t)r * NC4 + c4];
        float4 rp = rowp[(size_t)b * NROWS + r];  // broadcast load (same addr/group)
        float F     = scale * rp.x;               // scale*fac
        float alpha = rp.y;
        float TC    = scale * rp.z;               // scale*tc
        float SM    = fmaf(F, alpha, TC);         // scale*(fac*alpha+tc)
        float h  = rp.x * sqrtf(fmaxf(fmaf(alpha, alpha, -1.0f), 1e-8f));
        float nu = fmaxf(scale * h, 1e-4f);       // = sqrt(clip(linner,1e-8)) (isometry)
        float pt = scale * rp.w * invb;

        float4 tv;                                 // scaled x_T at origin
        tv.x = fmaf(-SM, mv.x, F * xv.x);
        tv.y = fmaf(-SM, mv.y, F * xv.y);
        tv.z = fmaf(-SM, mv.z, F * xv.z);
        tv.w = fmaf(-SM, mv.w, F * xv.w);
        if (c4 == 0) tv.x -= TC;

        float4 xo;                                 // PT origin -> beta
        xo.x = fmaf(pt, bv.x, tv.x);
        xo.y = fmaf(pt, bv.y, tv.y);
        xo.z = fmaf(pt, bv.z, tv.z);
        xo.w = fmaf(pt, bv.w, tv.w);
        if (c4 == 0) xo.x += pt;

        float ee = expf(nu);
        float ei = 1.0f / ee;
        float ch = 0.5f * (ee + ei);
        float so = 0.5f * (ee - ei) / nu;

        vf4 ov;
        ov.x = fmaf(ch, bv.x, so * xo.x);
        ov.y = fmaf(ch, bv.y, so * xo.y);
        ov.z = fmaf(ch, bv.z, so * xo.z);
        ov.w = fmaf(ch, bv.w, so * xo.w);
        // non-temporal: don't let `out` evict x from Infinity Cache
        __builtin_nontemporal_store(ov, (vf4*)&ob[(size_t)r * NC4 + c4]);
    }
}

// ---------- fallback (ws too small): recompute-with-reduce path ----------
__global__ __launch_bounds__(256) void k_var_slow(const float4* __restrict__ x,
                                                  const float* __restrict__ mean,
                                                  float* __restrict__ varsum) {
    int b   = blockIdx.x / BPB;
    int blk = blockIdx.x % BPB;
    int t   = threadIdx.x;
    int c4  = t & 31;
    int grp = t >> 5;
    int src = t & 32;
    const float* meanb = mean + b * CCH;
    float4 mv = ((const float4*)meanb)[c4];
    float  m0 = meanb[0];
    const float4* xb = x + (size_t)b * NROWS * NC4;
    int row0 = blk * RPB;
    float nsum = 0.0f;
    for (int r = row0 + grp; r < row0 + RPB; r += 8) {
        float4 xv = xb[(size_t)r * NC4 + c4];
        float d = grp_reduce(dot4(mv, xv));
        float x0 = __shfl(xv.x, src);
        float alpha = fmaxf(fmaf(2.0f * m0, x0, -d), 1.0f + 1e-7f);
        nsum += acoshf(alpha);
    }
    if (c4 == 0) atomicAdd(&varsum[b], nsum);
}

__global__ __launch_bounds__(256) void k_out_slow(const float4* __restrict__ x,
                                                  const float* __restrict__ mean,
                                                  const float* __restrict__ varsum,
                                                  const float* __restrict__ beta,
                                                  const float* __restrict__ gamma,
                                                  const float* __restrict__ lbm,
                                                  float4* __restrict__ out) {
    int b   = blockIdx.x / BPB;
    int blk = blockIdx.x % BPB;
    int t   = threadIdx.x;
    int c4  = t & 31;
    int grp = t >> 5;
    int src = t & 32;
    const float* meanb = mean + b * CCH;
    float4 mv = ((const float4*)meanb)[c4];
    float  m0 = meanb[0];
    float  inv1pm0 = 1.0f / (1.0f + m0);
    float4 bv = ((const float4*)beta)[c4];
    float  b0 = beta[0];
    float  invb  = 1.0f / (1.0f + b0);
    float  lbmb  = lbm[b];
    float  scale = gamma[0] / (varsum[b] * (1.0f / (float)NROWS) + 1e-5f);
    const float4* xb = x + (size_t)b * NROWS * NC4;
    float4*       ob = out + (size_t)b * NROWS * NC4;
    int row0 = blk * RPB;
    for (int r = row0 + grp; r < row0 + RPB; r += 8) {
        float4 xv = xb[(size_t)r * NC4 + c4];
        float d = dot4(mv, xv);
        float e = dot4(bv, xv);
        d += __shfl_xor(d, 1);  e += __shfl_xor(e, 1);
        d += __shfl_xor(d, 2);  e += __shfl_xor(e, 2);
        d += __shfl_xor(d, 4);  e += __shfl_xor(e, 4);
        d += __shfl_xor(d, 8);  e += __shfl_xor(e, 8);
        d += __shfl_xor(d, 16); e += __shfl_xor(e, 16);
        float x0 = __shfl(xv.x, src);
        float alpha = fmaxf(fmaf(2.0f * m0, x0, -d), 1.0f + 1e-7f);
        float h  = acoshf(alpha);
        float un = sqrtf(fmaxf(fmaf(alpha, alpha, -1.0f), 1e-8f));
        float fac = h / un;
        float u0  = fmaf(-alpha, m0, x0);
        float tc  = fac * u0 * inv1pm0;
        float s_m = fmaf(fac, alpha, tc);
        float lbx = fmaf(-2.0f * b0, x0, e);
        float pb  = fmaf(fac, lbx, fmaf(-s_m, lbmb, tc * b0));

        float F  = scale * fac;
        float TC = scale * tc;
        float SM = scale * s_m;
        float nu = fmaxf(scale * h, 1e-4f);
        float pt = scale * pb * invb;

        float4 tv;
        tv.x = fmaf(-SM, mv.x, F * xv.x);
        tv.y = fmaf(-SM, mv.y, F * xv.y);
        tv.z = fmaf(-SM, mv.z, F * xv.z);
        tv.w = fmaf(-SM, mv.w, F * xv.w);
        if (c4 == 0) tv.x -= TC;
        float4 xo;
        xo.x = fmaf(pt, bv.x, tv.x);
        xo.y = fmaf(pt, bv.y, tv.y);
        xo.z = fmaf(pt, bv.z, tv.z);
        xo.w = fmaf(pt, bv.w, tv.w);
        if (c4 == 0) xo.x += pt;
        float ee = expf(nu);
        float ei = 1.0f / ee;
        float ch = 0.5f * (ee + ei);
        float so = 0.5f * (ee - ei) / nu;
        vf4 ov;
        ov.x = fmaf(ch, bv.x, so * xo.x);
        ov.y = fmaf(ch, bv.y, so * xo.y);
        ov.z = fmaf(ch, bv.z, so * xo.z);
        ov.w = fmaf(ch, bv.w, so * xo.w);
        __builtin_nontemporal_store(ov, (vf4*)&ob[(size_t)r * NC4 + c4]);
    }
}

// ---------- launch ----------
extern "C" void kernel_launch(void* const* d_in, const int* in_sizes, int n_in,
                              void* d_out, int out_size, void* d_ws, size_t ws_size,
                              hipStream_t stream) {
    const float* x     = (const float*)d_in[0];
    const float* beta  = (const float*)d_in[1];
    const float* gamma = (const float*)d_in[2];
    float*       out   = (float*)d_out;

    float* ws     = (float*)d_ws;
    float* msum   = ws;                  // 8192 floats
    float* varsum = ws + 8192;           // 64
    float* mean   = ws + 8256;           // 8192
    float* lbm    = ws + 16448;          // 64
    float4* rowp  = (float4*)((char*)d_ws + 66048);     // 16B aligned
    size_t need   = 66048 + (size_t)BS * NROWS * 16;    // ~4.26 MB
    bool fast = ws_size >= need;

    hipMemsetAsync(ws, 0, (8192 + 64) * sizeof(float), stream);

    k_mean_sum<<<dim3(BS * BPB), dim3(256), 0, stream>>>((const float4*)x, msum);
    k_mean_norm<<<dim3(BS), dim3(128), 0, stream>>>(msum, beta, mean, lbm);
    if (fast) {
        k_var_fast<<<dim3(BS * BPB), dim3(256), 0, stream>>>(
            (const float4*)x, mean, beta, lbm, varsum, rowp);
        k_out_fast<<<dim3(BS * BPB), dim3(256), 0, stream>>>(
            (const float4*)x, mean, varsum, beta, gamma, rowp, (float4*)out);
    } else {
        k_var_slow<<<dim3(BS * BPB), dim3(256), 0, stream>>>(
            (const float4*)x, mean, varsum);
        k_out_slow<<<dim3(BS * BPB), dim3(256), 0, stream>>>(
            (const float4*)x, mean, varsum, beta, gamma, lbm, (float4*)out);
    }
}

// Round 3
// 282.400 us; speedup vs baseline: 1.4141x; 1.2405x over previous
//
#include <hip/hip_runtime.h>
#include <math.h>

// Problem constants (from reference setup_inputs)
#define BS    64
#define NROWS 4096          // H*W
#define CCH   128           // channels
#define NC4   32            // channels / 4
#define BPB   32            // blocks per batch for k_mean_sum / k_out
#define RPB   (NROWS/BPB)   // 128 rows per block

typedef float vf4 __attribute__((ext_vector_type(4)));

__device__ __forceinline__ float dot4(float4 a, float4 b) {
    return a.x*b.x + a.y*b.y + a.z*b.z + a.w*b.w;
}

// ---------- kernel 1: per-batch channel sums ----------
__global__ __launch_bounds__(256) void k_mean_sum(const float4* __restrict__ x,
                                                  float* __restrict__ msum) {
    int b   = blockIdx.x / BPB;
    int blk = blockIdx.x % BPB;
    int t   = threadIdx.x;
    int c4  = t & 31;
    int grp = t >> 5;
    int row0 = blk * RPB;
    const float4* xb = x + (size_t)b * NROWS * NC4;

    float4 acc = make_float4(0.f, 0.f, 0.f, 0.f);
    for (int r = row0 + grp; r < row0 + RPB; r += 8) {
        float4 v = xb[(size_t)r * NC4 + c4];
        acc.x += v.x; acc.y += v.y; acc.z += v.z; acc.w += v.w;
    }
    __shared__ float4 lds[256];
    lds[t] = acc;
    __syncthreads();
    if (t < 32) {
        float4 s = lds[t];
        #pragma unroll
        for (int k = 1; k < 8; ++k) {
            float4 v = lds[t + 32 * k];
            s.x += v.x; s.y += v.y; s.z += v.z; s.w += v.w;
        }
        atomicAdd(&msum[b * CCH + 4 * t + 0], s.x);
        atomicAdd(&msum[b * CCH + 4 * t + 1], s.y);
        atomicAdd(&msum[b * CCH + 4 * t + 2], s.z);
        atomicAdd(&msum[b * CCH + 4 * t + 3], s.w);
    }
}

// ---------- kernel 2: per-row params (quad-per-row) + variance + mean ----------
// 1024 blocks of 256 threads; block = (batch b, 256 consecutive rows).
// In-block: normalize mean from msum (replaces old k_mean_norm).
// Per row: 4 lanes, each lane 8 float4 chunks (64B-contiguous per quad).
__global__ __launch_bounds__(256) void k_rows(const float4* __restrict__ x,
                                              const float* __restrict__ msum,
                                              const float* __restrict__ beta,
                                              float* __restrict__ mean,
                                              float* __restrict__ varsum,
                                              float4* __restrict__ rowp) {
    int blk = blockIdx.x;            // 0..1023
    int b   = blk >> 4;              // 16 blocks per batch
    int sub = blk & 15;
    int t   = threadIdx.x;

    __shared__ float  sm[128];       // raw mean m (pre-normalization)
    __shared__ float4 mvs[32];       // normalized mean
    __shared__ float4 bvs[32];       // beta
    __shared__ float2 red2[256];
    __shared__ float  redh[256];

    float m = 0.f, bc = 0.f;
    if (t < 128) {
        m  = msum[b * CCH + t] * (1.0f / (float)NROWS);
        bc = beta[t];
        sm[t] = m;
    }
    red2[t] = make_float2(m * m, bc * m);
    __syncthreads();
    #pragma unroll
    for (int s = 128; s > 0; s >>= 1) {
        if (t < s) { red2[t].x += red2[t + s].x; red2[t].y += red2[t + s].y; }
        __syncthreads();
    }
    float smm = red2[0].x, sbm = red2[0].y;
    float m0  = sm[0];
    float val = fmaf(2.f * m0, m0, -smm);                 // -linner(m,m)
    float inv = __builtin_amdgcn_rsqf(fmaxf(val, 1e-8f));
    float mean0   = m0 * inv;
    float inv1pm0 = __builtin_amdgcn_rcpf(1.0f + mean0);
    float b0  = beta[0];
    float lbm = (sbm - 2.f * b0 * m0) * inv;              // linner(beta, mean)
    if (t < 128) {
        float mc = sm[t] * inv;
        ((float*)mvs)[t] = mc;
        ((float*)bvs)[t] = bc;
        if (sub == 0) mean[b * CCH + t] = mc;
    }
    __syncthreads();

    int lane = t & 63, wave = t >> 6;
    int q  = lane >> 2;              // row-within-16
    int ql = lane & 3;               // chunk phase
    int srcl = lane & ~3;            // quad base lane
    float nsum = 0.f;

    #pragma unroll
    for (int o = 0; o < 4; ++o) {
        int row = sub * 256 + o * 64 + wave * 16 + q;
        const float4* xr = x + ((size_t)b * NROWS + row) * NC4;

        // c = 0 peeled to capture channel 0
        float4 xv = xr[ql];
        float4 mv = mvs[ql];
        float4 bv = bvs[ql];
        float x00 = xv.x;            // valid on ql==0 lanes
        float d = dot4(xv, mv);
        float e = dot4(xv, bv);
        #pragma unroll
        for (int c = 1; c < 8; ++c) {
            int c4 = 4 * c + ql;     // quad covers 64B contiguous
            xv = xr[c4];
            mv = mvs[c4];
            bv = bvs[c4];
            d = fmaf(xv.x, mv.x, fmaf(xv.y, mv.y, fmaf(xv.z, mv.z, fmaf(xv.w, mv.w, d))));
            e = fmaf(xv.x, bv.x, fmaf(xv.y, bv.y, fmaf(xv.z, bv.z, fmaf(xv.w, bv.w, e))));
        }
        d += __shfl_xor(d, 1);  e += __shfl_xor(e, 1);
        d += __shfl_xor(d, 2);  e += __shfl_xor(e, 2);
        float x0 = __shfl(x00, srcl);

        float alpha = fmaxf(fmaf(2.f * mean0, x0, -d), 1.0f + 1e-7f);
        float a2m1  = fmaxf(fmaf(alpha, alpha, -1.f), 1e-8f);   // linner(u,u) = a^2-1
        float sq    = sqrtf(a2m1);
        float h     = __logf(alpha + sq);                        // acosh(alpha)
        float fac   = h * __builtin_amdgcn_rcpf(sq);
        float u0    = fmaf(-alpha, mean0, x0);
        float tc    = fac * u0 * inv1pm0;
        float s_m   = fmaf(fac, alpha, tc);    // x_T = fac*x - s_m*mean - tc*e0
        float lbx   = fmaf(-2.f * b0, x0, e);  // linner(beta, x)
        float pb    = fmaf(fac, lbx, fmaf(-s_m, lbm, tc * b0)); // linner(beta, x_T)
        if (ql == 0) rowp[(size_t)b * NROWS + row] = make_float4(fac, alpha, tc, pb);
        nsum += 0.25f * h;           // h identical across quad; 0.25f exact
    }

    redh[t] = nsum;
    __syncthreads();
    #pragma unroll
    for (int s = 128; s > 0; s >>= 1) {
        if (t < s) redh[t] += redh[t + s];
        __syncthreads();
    }
    if (t == 0) atomicAdd(&varsum[b], redh[0]);
}

// ---------- kernel 3: reduction-free output, 3 FMA / element ----------
__global__ __launch_bounds__(256) void k_out(const float4* __restrict__ x,
                                             const float* __restrict__ mean,
                                             const float* __restrict__ varsum,
                                             const float* __restrict__ beta,
                                             const float* __restrict__ gamma,
                                             const float4* __restrict__ rowp,
                                             float4* __restrict__ out) {
    int b   = blockIdx.x / BPB;
    int blk = blockIdx.x % BPB;
    int t   = threadIdx.x;
    int c4  = t & 31;
    int grp = t >> 5;

    const float* meanb = mean + b * CCH;
    float4 mv = ((const float4*)meanb)[c4];
    float4 bv = ((const float4*)beta)[c4];
    float  b0 = beta[0];
    float  invb  = __builtin_amdgcn_rcpf(1.0f + b0);
    float  scale = gamma[0] * __builtin_amdgcn_rcpf(
                        varsum[b] * (1.0f / (float)NROWS) + 1e-5f);

    const float4* xb = x + (size_t)b * NROWS * NC4;
    float4*       ob = out + (size_t)b * NROWS * NC4;
    int row0 = blk * RPB;

    for (int r = row0 + grp; r < row0 + RPB; r += 8) {
        float4 xv = xb[(size_t)r * NC4 + c4];
        float4 rp = rowp[(size_t)b * NROWS + r];   // broadcast within group
        float fac = rp.x, alpha = rp.y, tcv = rp.z, pb = rp.w;

        float F   = scale * fac;
        float TCv = scale * tcv;
        float SM  = fmaf(F, alpha, TCv);
        float sq  = sqrtf(fmaxf(fmaf(alpha, alpha, -1.f), 1e-8f));
        float nu  = fmaxf(scale * (fac * sq), 1e-4f);  // = sqrt(clip(linner,1e-8))
        float PT  = scale * pb * invb;

        float ee = __expf(nu);
        float ei = __builtin_amdgcn_rcpf(ee);
        float ch = 0.5f * (ee + ei);
        float so = 0.5f * (ee - ei) * __builtin_amdgcn_rcpf(nu);

        float A = so * F;
        float B = -so * SM;
        float C = fmaf(so, PT, ch);
        float D = so * (PT - TCv);

        vf4 ov;
        ov.x = fmaf(A, xv.x, fmaf(B, mv.x, C * bv.x));
        ov.y = fmaf(A, xv.y, fmaf(B, mv.y, C * bv.y));
        ov.z = fmaf(A, xv.z, fmaf(B, mv.z, C * bv.z));
        ov.w = fmaf(A, xv.w, fmaf(B, mv.w, C * bv.w));
        if (c4 == 0) ov.x += D;
        // non-temporal full-line store: don't evict x from L3
        __builtin_nontemporal_store(ov, (vf4*)&ob[(size_t)r * NC4 + c4]);
    }
}

// ---------- launch ----------
extern "C" void kernel_launch(void* const* d_in, const int* in_sizes, int n_in,
                              void* d_out, int out_size, void* d_ws, size_t ws_size,
                              hipStream_t stream) {
    const float* x     = (const float*)d_in[0];
    const float* beta  = (const float*)d_in[1];
    const float* gamma = (const float*)d_in[2];
    float*       out   = (float*)d_out;

    float* ws     = (float*)d_ws;
    float* msum   = ws;                  // 8192 floats
    float* varsum = ws + 8192;           // 64
    float* mean   = ws + 8256;           // 8192
    float4* rowp  = (float4*)((char*)d_ws + 65792);   // 16B-aligned, 4 MB

    hipMemsetAsync(ws, 0, (8192 + 64) * sizeof(float), stream);

    k_mean_sum<<<dim3(BS * BPB), dim3(256), 0, stream>>>((const float4*)x, msum);
    k_rows<<<dim3(1024), dim3(256), 0, stream>>>(
        (const float4*)x, msum, beta, mean, varsum, rowp);
    k_out<<<dim3(BS * BPB), dim3(256), 0, stream>>>(
        (const float4*)x, mean, varsum, beta, gamma, rowp, (float4*)out);
}